// Round 1
// baseline (1865.106 us; speedup 1.0000x reference)
//
#include <hip/hip_runtime.h>
#include <stdint.h>

// Problem: h[4096,512] fp32, A[32768,512] fp32.
// out[b] = argmax_k cos(h_b, A_k)  (int32, first index on ties)
// Key simplification: argmax invariant to positive scale of h_b -> only A needs
// normalization, applied as score = dot(h,A_k) * rnorm[k] after accumulation.

#define DIM 512
#define B_ROWS 4096
#define K_ROWS 32768
#define BT 128          // h-rows per block tile
#define KT 128          // A-rows per k-iteration
#define BK 32           // D-slice staged per LDS step
#define LDS_STRIDE 132  // 128 + 4 pad (write-conflict mitigation, keeps 16B align)
#define KSLICES 32
#define KITERS 8        // (K_ROWS / KSLICES) / KT

__device__ __forceinline__ unsigned int float_to_ord(float s) {
    // monotone float->uint map (preserves ordering incl. negatives)
    unsigned int u = __float_as_uint(s);
    return (u & 0x80000000u) ? ~u : (u | 0x80000000u);
}

__global__ __launch_bounds__(256) void init_ws_kernel(unsigned long long* packed) {
    int i = blockIdx.x * 256 + threadIdx.x;
    if (i < B_ROWS) packed[i] = 0ULL;  // below any real packed score
}

// 1/max(||A_k||, eps) for all K rows; one wave per row.
__global__ __launch_bounds__(256) void rnorm_kernel(const float* __restrict__ A,
                                                    float* __restrict__ rn) {
    int wave = threadIdx.x >> 6;
    int lane = threadIdx.x & 63;
    int row = blockIdx.x * 4 + wave;
    const float4* p = (const float4*)(A + (size_t)row * DIM);
    float4 a = p[lane];       // d = lane*4
    float4 b = p[64 + lane];  // d = 256 + lane*4
    float s = a.x*a.x + a.y*a.y + a.z*a.z + a.w*a.w
            + b.x*b.x + b.y*b.y + b.z*b.z + b.w*b.w;
    #pragma unroll
    for (int off = 32; off > 0; off >>= 1) s += __shfl_down(s, off, 64);
    if (lane == 0) {
        float n = sqrtf(s);
        rn[row] = 1.0f / fmaxf(n, 1e-8f);
    }
}

// Fused fp32 GEMM + argmax. Block: 256 threads = 16(tx,k) x 16(ty,b),
// 8x8 micro-tile split as 2x4 + 2x4 (conflict-free LDS reads).
__global__ __launch_bounds__(256, 4) void score_kernel(
    const float* __restrict__ h, const float* __restrict__ A,
    const float* __restrict__ rn, unsigned long long* __restrict__ packed)
{
    __shared__ __attribute__((aligned(16))) float hs[BK][LDS_STRIDE];
    __shared__ __attribute__((aligned(16))) float as[BK][LDS_STRIDE];

    const int t  = threadIdx.x;
    const int tx = t & 15;   // k dimension
    const int ty = t >> 4;   // b dimension
    const int b0 = blockIdx.x * BT;   // 32 b-tiles
    const int ks = blockIdx.y;        // 32 k-slices

    const int ldr = t >> 3;          // staging row 0..31
    const int ldc = (t & 7) * 4;     // staging col 0,4,...,28

    float bestv[8];
    unsigned int besti[8];
    #pragma unroll
    for (int i = 0; i < 8; i++) { bestv[i] = -3.0e38f; besti[i] = 0u; }

    for (int it = 0; it < KITERS; ++it) {
        const int k0 = ks * (K_ROWS / KSLICES) + it * KT;

        float acc[8][8];
        #pragma unroll
        for (int i = 0; i < 8; i++)
            #pragma unroll
            for (int j = 0; j < 8; j++) acc[i][j] = 0.0f;

        for (int dsb = 0; dsb < DIM; dsb += BK) {
            // ---- stage BTxBK of h and KTxBK of A, transposed to [d][row] ----
            #pragma unroll
            for (int p = 0; p < 4; p++) {
                int r = ldr + 32 * p;
                float4 hv = *(const float4*)(h + (size_t)(b0 + r) * DIM + dsb + ldc);
                float4 av = *(const float4*)(A + (size_t)(k0 + r) * DIM + dsb + ldc);
                hs[ldc + 0][r] = hv.x; hs[ldc + 1][r] = hv.y;
                hs[ldc + 2][r] = hv.z; hs[ldc + 3][r] = hv.w;
                as[ldc + 0][r] = av.x; as[ldc + 1][r] = av.y;
                as[ldc + 2][r] = av.z; as[ldc + 3][r] = av.w;
            }
            __syncthreads();

            #pragma unroll
            for (int d = 0; d < BK; ++d) {
                float4 a0 = *(const float4*)&as[d][tx * 4];
                float4 a1 = *(const float4*)&as[d][64 + tx * 4];
                float4 h0 = *(const float4*)&hs[d][ty * 4];
                float4 h1 = *(const float4*)&hs[d][64 + ty * 4];
                float av[8] = {a0.x, a0.y, a0.z, a0.w, a1.x, a1.y, a1.z, a1.w};
                float hv[8] = {h0.x, h0.y, h0.z, h0.w, h1.x, h1.y, h1.z, h1.w};
                #pragma unroll
                for (int i = 0; i < 8; i++)
                    #pragma unroll
                    for (int j = 0; j < 8; j++)
                        acc[i][j] += hv[i] * av[j];
            }
            __syncthreads();
        }

        // ---- fused scoring + running argmax (first-index tie semantics) ----
        #pragma unroll
        for (int j = 0; j < 8; j++) {
            int kl = (j < 4) ? (tx * 4 + j) : (64 + tx * 4 + (j - 4));
            unsigned int kg = (unsigned int)(k0 + kl);
            float r = rn[kg];
            #pragma unroll
            for (int i = 0; i < 8; i++) {
                float s = acc[i][j] * r;
                if (s > bestv[i] || (s == bestv[i] && kg < besti[i])) {
                    bestv[i] = s; besti[i] = kg;
                }
            }
        }
    }

    // ---- cross-lane (width 16, same ty group) argmax reduce, then atomic ----
    #pragma unroll
    for (int i = 0; i < 8; i++) {
        float v = bestv[i];
        unsigned int ix = besti[i];
        #pragma unroll
        for (int off = 8; off > 0; off >>= 1) {
            float ov = __shfl_xor(v, off, 16);
            unsigned int oi = __shfl_xor(ix, off, 16);
            if (ov > v || (ov == v && oi < ix)) { v = ov; ix = oi; }
        }
        if (tx == 0) {
            int bg = b0 + ((i < 4) ? (ty * 4 + i) : (64 + ty * 4 + (i - 4)));
            // inverted idx in low bits -> atomicMax picks smallest idx on ties
            unsigned long long pk =
                ((unsigned long long)float_to_ord(v) << 32) |
                (unsigned long long)(0xFFFFFFFFu - ix);
            atomicMax(packed + bg, pk);
        }
    }
}

__global__ __launch_bounds__(256) void finalize_kernel(
    const unsigned long long* __restrict__ packed, int* __restrict__ out)
{
    int i = blockIdx.x * 256 + threadIdx.x;
    if (i < B_ROWS)
        out[i] = (int)(0xFFFFFFFFu - (unsigned int)(packed[i] & 0xFFFFFFFFull));
}

extern "C" void kernel_launch(void* const* d_in, const int* in_sizes, int n_in,
                              void* d_out, int out_size, void* d_ws, size_t ws_size,
                              hipStream_t stream) {
    const float* h = (const float*)d_in[0];   // [4096, 512]
    const float* A = (const float*)d_in[1];   // [32768, 512]
    int* out = (int*)d_out;                   // [4096] int32

    // ws layout: [0, 32KB) packed u64 per b-row; [32KB, 160KB) rnorm[K]
    unsigned long long* packed = (unsigned long long*)d_ws;
    float* rn = (float*)((char*)d_ws + (size_t)B_ROWS * sizeof(unsigned long long));

    init_ws_kernel<<<B_ROWS / 256, 256, 0, stream>>>(packed);
    rnorm_kernel<<<K_ROWS / 4, 256, 0, stream>>>(A, rn);
    dim3 grid(B_ROWS / BT, KSLICES);
    score_kernel<<<grid, 256, 0, stream>>>(h, A, rn, packed);
    finalize_kernel<<<B_ROWS / 256, 256, 0, stream>>>(packed, out);
}

// Round 2
// 594.425 us; speedup vs baseline: 3.1377x; 3.1377x over previous
//
#include <hip/hip_runtime.h>
#include <stdint.h>

// out[b] = argmax_k cos(h_b, A_k). Screen with bf16-split MFMA (hi*hi + hi*lo
// + lo*hi, fp32 acc), keep per-row top-2 per block, refine candidates in fp32.

#define DIM 512
#define B_ROWS 4096
#define K_ROWS 32768
#define BT 128
#define KT 128
#define NKTILES (K_ROWS / KT)   // 256
#define KSLOTS 24               // k-blocks per b-row; grid = 32*24 = 768
#define BK 32
#define STR 40                  // ushort row stride (32 + 8 pad, 80 B)
#define TILE_US (BT * STR)      // 5120 ushorts = 10240 B per tile

typedef __attribute__((ext_vector_type(8))) short short8;
typedef __attribute__((ext_vector_type(4))) float fx4;
typedef unsigned long long u64;

__device__ __forceinline__ uint32_t ford(float s) {
    uint32_t u = __float_as_uint(s);
    uint32_t m = (uint32_t)((int32_t)u >> 31);
    return u ^ (m | 0x80000000u);
}
__device__ __forceinline__ u64 umax64(u64 a, u64 b) { return a > b ? a : b; }
__device__ __forceinline__ u64 umin64(u64 a, u64 b) { return a < b ? a : b; }

// pack bf16(a0) | bf16(a1)<<16 via byte-perm (bit truncation)
__device__ __forceinline__ uint32_t hi_pair(float a0, float a1) {
    return __builtin_amdgcn_perm(__float_as_uint(a1), __float_as_uint(a0), 0x07060302u);
}
__device__ __forceinline__ float lo_of(float a) {
    return a - __uint_as_float(__float_as_uint(a) & 0xFFFF0000u);
}

// 1/max(||A_k||, eps); one wave per row.
__global__ __launch_bounds__(256) void rnorm_kernel(const float* __restrict__ A,
                                                    float* __restrict__ rn) {
    int wave = threadIdx.x >> 6;
    int lane = threadIdx.x & 63;
    int row = blockIdx.x * 4 + wave;
    const fx4* p = (const fx4*)(A + (size_t)row * DIM);
    fx4 a = p[lane];
    fx4 b = p[64 + lane];
    float s = a[0]*a[0] + a[1]*a[1] + a[2]*a[2] + a[3]*a[3]
            + b[0]*b[0] + b[1]*b[1] + b[2]*b[2] + b[3]*b[3];
    #pragma unroll
    for (int off = 32; off > 0; off >>= 1) s += __shfl_down(s, off, 64);
    if (lane == 0) {
        float n = sqrtf(s);
        rn[row] = 1.0f / fmaxf(n, 1e-8f);
    }
}

__global__ __launch_bounds__(256, 3) void score_kernel(
    const float* __restrict__ h, const float* __restrict__ A,
    const float* __restrict__ rn, u64* __restrict__ cand)
{
    __shared__ __attribute__((aligned(16))) unsigned short smem[4 * TILE_US];
    unsigned short* hs_hi = smem;
    unsigned short* hs_lo = smem + TILE_US;
    unsigned short* as_hi = smem + 2 * TILE_US;
    unsigned short* as_lo = smem + 3 * TILE_US;

    const int t = threadIdx.x;
    const int lane = t & 63;
    const int wid = t >> 6;
    const int wm = wid >> 1, wn = wid & 1;
    const int btile = blockIdx.x / KSLOTS;
    const int kslot = blockIdx.x % KSLOTS;
    const int b0 = btile * BT;

    const int sr = t >> 3;        // staging row 0..31
    const int sc = (t & 7) * 4;   // staging col 0..28

    const int lr = lane & 15;     // frag row-within-16 / C col
    const int q  = lane >> 4;     // C row quad

    u64 run1 = 0, run2 = 0;

    for (int kt = kslot; kt < NKTILES; kt += KSLOTS) {
        const int k0 = kt * KT;

        float rnv[4]; uint32_t nk[4];
        #pragma unroll
        for (int ni = 0; ni < 4; ni++) {
            int kg = k0 + wn * 64 + ni * 16 + lr;
            rnv[ni] = rn[kg];
            nk[ni] = ~(uint32_t)kg;
        }

        fx4 acc[4][4];
        #pragma unroll
        for (int mi = 0; mi < 4; mi++)
            #pragma unroll
            for (int ni = 0; ni < 4; ni++)
                acc[mi][ni] = (fx4){0.f, 0.f, 0.f, 0.f};

        for (int dc = 0; dc < DIM; dc += BK) {
            __syncthreads();
            #pragma unroll
            for (int i = 0; i < 4; i++) {
                int r = sr + 32 * i;
                fx4 hv = *reinterpret_cast<const fx4*>(h + (size_t)(b0 + r) * DIM + dc + sc);
                fx4 av = *reinterpret_cast<const fx4*>(A + (size_t)(k0 + r) * DIM + dc + sc);
                uint32_t hh01 = hi_pair(hv[0], hv[1]);
                uint32_t hh23 = hi_pair(hv[2], hv[3]);
                uint32_t hl01 = hi_pair(lo_of(hv[0]), lo_of(hv[1]));
                uint32_t hl23 = hi_pair(lo_of(hv[2]), lo_of(hv[3]));
                uint32_t ah01 = hi_pair(av[0], av[1]);
                uint32_t ah23 = hi_pair(av[2], av[3]);
                uint32_t al01 = hi_pair(lo_of(av[0]), lo_of(av[1]));
                uint32_t al23 = hi_pair(lo_of(av[2]), lo_of(av[3]));
                int off = r * STR + sc;
                *reinterpret_cast<uint2*>(&hs_hi[off]) = make_uint2(hh01, hh23);
                *reinterpret_cast<uint2*>(&hs_lo[off]) = make_uint2(hl01, hl23);
                *reinterpret_cast<uint2*>(&as_hi[off]) = make_uint2(ah01, ah23);
                *reinterpret_cast<uint2*>(&as_lo[off]) = make_uint2(al01, al23);
            }
            __syncthreads();

            short8 hfh[4], hfl[4], afh[4], afl[4];
            #pragma unroll
            for (int mi = 0; mi < 4; mi++) {
                int off = (wm * 64 + mi * 16 + lr) * STR + q * 8;
                hfh[mi] = *reinterpret_cast<const short8*>(&hs_hi[off]);
                hfl[mi] = *reinterpret_cast<const short8*>(&hs_lo[off]);
            }
            #pragma unroll
            for (int ni = 0; ni < 4; ni++) {
                int off = (wn * 64 + ni * 16 + lr) * STR + q * 8;
                afh[ni] = *reinterpret_cast<const short8*>(&as_hi[off]);
                afl[ni] = *reinterpret_cast<const short8*>(&as_lo[off]);
            }
            #pragma unroll
            for (int mi = 0; mi < 4; mi++)
                #pragma unroll
                for (int ni = 0; ni < 4; ni++) {
                    acc[mi][ni] = __builtin_amdgcn_mfma_f32_16x16x32_bf16(hfh[mi], afh[ni], acc[mi][ni], 0, 0, 0);
                    acc[mi][ni] = __builtin_amdgcn_mfma_f32_16x16x32_bf16(hfh[mi], afl[ni], acc[mi][ni], 0, 0, 0);
                    acc[mi][ni] = __builtin_amdgcn_mfma_f32_16x16x32_bf16(hfl[mi], afh[ni], acc[mi][ni], 0, 0, 0);
                }
        }

        // epilogue: per-row top-2 of this k-tile, merged into running top-2
        #pragma unroll
        for (int mi = 0; mi < 4; mi++) {
            #pragma unroll
            for (int r = 0; r < 4; r++) {
                u64 p[4];
                #pragma unroll
                for (int ni = 0; ni < 4; ni++) {
                    float s = acc[mi][ni][r] * rnv[ni];
                    p[ni] = ((u64)ford(s) << 32) | (u64)nk[ni];
                }
                u64 h01 = umax64(p[0], p[1]), l01 = umin64(p[0], p[1]);
                u64 h23 = umax64(p[2], p[3]), l23 = umin64(p[2], p[3]);
                u64 v1 = umax64(h01, h23);
                u64 v2 = umax64(umin64(h01, h23), umax64(l01, l23));
                #pragma unroll
                for (int m = 1; m <= 8; m <<= 1) {
                    u64 w1 = __shfl_xor(v1, m, 64);
                    u64 w2 = __shfl_xor(v2, m, 64);
                    u64 n1 = umax64(v1, w1);
                    u64 n2 = umax64(umin64(v1, w1), umax64(v2, w2));
                    v1 = n1; v2 = n2;
                }
                if (lr == mi * 4 + r) {
                    u64 n1 = umax64(run1, v1);
                    u64 n2 = umax64(umin64(run1, v1), umax64(run2, v2));
                    run1 = n1; run2 = n2;
                }
            }
        }
    }

    // merge the two wn-halves through LDS, write block top-2 per row
    __syncthreads();
    u64* cl = reinterpret_cast<u64*>(smem);   // [128][4]
    {
        int row_local = wm * 64 + (lr >> 2) * 16 + q * 4 + (lr & 3);
        cl[row_local * 4 + wn * 2 + 0] = run1;
        cl[row_local * 4 + wn * 2 + 1] = run2;
    }
    __syncthreads();
    if (t < BT) {
        u64 a1 = cl[t * 4 + 0], a2 = cl[t * 4 + 1];
        u64 b1 = cl[t * 4 + 2], b2 = cl[t * 4 + 3];
        u64 g1 = umax64(a1, b1);
        u64 g2 = umax64(umin64(a1, b1), umax64(a2, b2));
        size_t base = ((size_t)(b0 + t) * KSLOTS + kslot) * 2;
        cand[base] = g1;
        cand[base + 1] = g2;
    }
}

// one wave per row: top-4 of 48 candidates, exact fp32 rescore, argmax.
__global__ __launch_bounds__(256) void refine_kernel(
    const float* __restrict__ h, const float* __restrict__ A,
    const float* __restrict__ rn, const u64* __restrict__ cand,
    int* __restrict__ out)
{
    const int t = threadIdx.x, lane = t & 63, wid = t >> 6;
    const int row = blockIdx.x * 4 + wid;
    const u64* cr = cand + (size_t)row * (KSLOTS * 2);
    u64 x = (lane < KSLOTS * 2) ? cr[lane] : 0ULL;

    u64 sel[4];
    #pragma unroll
    for (int j = 0; j < 4; j++) {
        u64 v = x;
        #pragma unroll
        for (int m = 32; m >= 1; m >>= 1) v = umax64(v, __shfl_xor(v, m, 64));
        sel[j] = v;
        if (x == v) x = 0;
    }

    const fx4* hp = reinterpret_cast<const fx4*>(h + (size_t)row * DIM);
    fx4 h0 = hp[lane * 2], h1 = hp[lane * 2 + 1];

    u64 best = 0;
    #pragma unroll
    for (int j = 0; j < 4; j++) {
        uint32_t kg = ~(uint32_t)sel[j];
        const fx4* ap = reinterpret_cast<const fx4*>(A + (size_t)kg * DIM);
        fx4 a0 = ap[lane * 2], a1 = ap[lane * 2 + 1];
        float s = h0[0]*a0[0] + h0[1]*a0[1] + h0[2]*a0[2] + h0[3]*a0[3]
                + h1[0]*a1[0] + h1[1]*a1[1] + h1[2]*a1[2] + h1[3]*a1[3];
        #pragma unroll
        for (int m = 32; m >= 1; m >>= 1) s += __shfl_xor(s, m, 64);
        s *= rn[kg];
        u64 pk = ((u64)ford(s) << 32) | (u64)(~kg);
        best = umax64(best, pk);
    }
    if (lane == 0) out[row] = (int)(~(uint32_t)best);
}

extern "C" void kernel_launch(void* const* d_in, const int* in_sizes, int n_in,
                              void* d_out, int out_size, void* d_ws, size_t ws_size,
                              hipStream_t stream) {
    const float* h = (const float*)d_in[0];   // [4096, 512]
    const float* A = (const float*)d_in[1];   // [32768, 512]
    int* out = (int*)d_out;                   // [4096] int32

    // ws: cand u64[4096*24*2] (1.5 MB) then rn float[32768]
    u64* cand = (u64*)d_ws;
    float* rn = (float*)((char*)d_ws + (size_t)B_ROWS * KSLOTS * 2 * sizeof(u64));

    rnorm_kernel<<<K_ROWS / 4, 256, 0, stream>>>(A, rn);
    score_kernel<<<32 * KSLOTS, 256, 0, stream>>>(h, A, rn, cand);
    refine_kernel<<<B_ROWS / 4, 256, 0, stream>>>(h, A, rn, cand, out);
}

// Round 3
// 270.634 us; speedup vs baseline: 6.8916x; 2.1964x over previous
//
#include <hip/hip_runtime.h>
#include <stdint.h>

// out[b] = argmax_k cos(h_b, A_k), int32, first-index ties.
// Pass 1 (prep): rn[k]=1/max(||A_k||,eps); a16 = f16(A*rn); h16 = f16(h).
// Pass 2 (screen): f16 MFMA GEMM, per-row top-2 per block -> cand (u64 packed).
// Pass 3 (refine): exact fp32 rescore of top-4 of 48 candidates per row.

#define DIM 512
#define B_ROWS 4096
#define K_ROWS 32768
#define BT 128
#define KT 128
#define NKT (K_ROWS / KT)    // 256
#define KSLOTS 24            // grid = 32*24 = 768 blocks = 3/CU
#define BK 64                // halves per D-chunk
#define NCHUNK (DIM / BK)    // 8

typedef __attribute__((ext_vector_type(4))) float fx4;
typedef _Float16 f16;
typedef __attribute__((ext_vector_type(8))) _Float16 half8;
typedef unsigned long long u64;

__device__ __forceinline__ uint32_t ford(float s) {
    uint32_t u = __float_as_uint(s);
    return u ^ ((uint32_t)((int32_t)u >> 31) | 0x80000000u);
}
__device__ __forceinline__ u64 umax64(u64 a, u64 b) { return a > b ? a : b; }
__device__ __forceinline__ u64 umin64(u64 a, u64 b) { return a < b ? a : b; }
__device__ __forceinline__ uint32_t umax32(uint32_t a, uint32_t b) { return a > b ? a : b; }
__device__ __forceinline__ uint32_t umin32(uint32_t a, uint32_t b) { return a < b ? a : b; }

// one wave per A row: rn + normalized f16 conversion
__global__ __launch_bounds__(256) void prepA_kernel(const float* __restrict__ A,
                                                    f16* __restrict__ a16,
                                                    float* __restrict__ rn) {
    int lane = threadIdx.x & 63, wid = threadIdx.x >> 6;
    int row = blockIdx.x * 4 + wid;
    const fx4* p = (const fx4*)(A + (size_t)row * DIM);
    fx4 a = p[2 * lane], b = p[2 * lane + 1];
    float ss = a[0]*a[0] + a[1]*a[1] + a[2]*a[2] + a[3]*a[3]
             + b[0]*b[0] + b[1]*b[1] + b[2]*b[2] + b[3]*b[3];
    #pragma unroll
    for (int off = 32; off > 0; off >>= 1) ss += __shfl_xor(ss, off, 64);
    float r = 1.0f / fmaxf(sqrtf(ss), 1e-8f);
    if (lane == 0) rn[row] = r;
    half8 o;
    o[0] = (f16)(a[0]*r); o[1] = (f16)(a[1]*r); o[2] = (f16)(a[2]*r); o[3] = (f16)(a[3]*r);
    o[4] = (f16)(b[0]*r); o[5] = (f16)(b[1]*r); o[6] = (f16)(b[2]*r); o[7] = (f16)(b[3]*r);
    *reinterpret_cast<half8*>(a16 + (size_t)row * DIM + lane * 8) = o;
}

__global__ __launch_bounds__(256) void preph_kernel(const float* __restrict__ h,
                                                    f16* __restrict__ h16) {
    int i = blockIdx.x * 256 + threadIdx.x;  // group of 8 elements
    const fx4* p = (const fx4*)(h + (size_t)i * 8);
    fx4 a = p[0], b = p[1];
    half8 o;
    o[0] = (f16)a[0]; o[1] = (f16)a[1]; o[2] = (f16)a[2]; o[3] = (f16)a[3];
    o[4] = (f16)b[0]; o[5] = (f16)b[1]; o[6] = (f16)b[2]; o[7] = (f16)b[3];
    *reinterpret_cast<half8*>(h16 + (size_t)i * 8) = o;
}

typedef __attribute__((address_space(3))) uint32_t lds_u32;
typedef __attribute__((address_space(1))) const uint32_t g_u32;

__global__ __launch_bounds__(256, 3) void score_kernel(
    const f16* __restrict__ h16, const f16* __restrict__ a16,
    u64* __restrict__ cand)
{
    // tiles: hf [128][64]f16 @0 (16KB), af @16384 (16KB); reused as u64 cl[128][33]
    __shared__ __attribute__((aligned(16))) char smem[33792];
    char* hf = smem;
    char* af = smem + 16384;

    const int t = threadIdx.x, lane = t & 63, wid = t >> 6;
    const int wm = wid >> 1, wn = wid & 1;
    const int lr = lane & 15, q = lane >> 4;
    const int btile = blockIdx.x / KSLOTS, kslot = blockIdx.x % KSLOTS;
    const int b0 = btile * BT;

    // staging geometry: issue covers 8 rows (1KB); lane -> (row=lane>>3, slot=lane&7)
    // XOR swizzle: LDS granule slot s at row r holds source granule s^(r&7)
    const int srow = lane >> 3;
    const int scol = (lane & 7) ^ srow;

    // loop-invariant frag LDS byte offsets (swizzled)
    const int sw0 = ((q) ^ (lr & 7)) * 16;        // K-half 0: granule q
    const int sw1 = ((4 + q) ^ (lr & 7)) * 16;    // K-half 1: granule 4+q
    const int hrow = wm * 64 + lr;
    const int arow = wn * 64 + lr;

    uint32_t v1[16], v2[16];   // per-thread top-2, packed (ford&~63)|meta6
    #pragma unroll
    for (int s = 0; s < 16; s++) { v1[s] = 0u; v2[s] = 0u; }

    const f16* hbase = h16 + (size_t)b0 * DIM;
    char* mytile = (wid < 2) ? hf : af;
    const int ibase = (wid & 1) * 8;

    int it = 0;
    for (int kt = kslot; kt < NKT; kt += KSLOTS, it++) {
        const int k0 = kt * KT;
        const f16* mybase = (wid < 2) ? hbase : (a16 + (size_t)k0 * DIM);

        fx4 acc[4][4];
        #pragma unroll
        for (int mi = 0; mi < 4; mi++)
            #pragma unroll
            for (int ni = 0; ni < 4; ni++)
                acc[mi][ni] = (fx4){0.f, 0.f, 0.f, 0.f};

        for (int dc = 0; dc < NCHUNK; dc++) {
            __syncthreads();
            const char* src = (const char*)(mybase + dc * BK);
            #pragma unroll
            for (int i = 0; i < 8; i++) {
                int issue = ibase + i;
                const char* g = src + (size_t)(issue * 8 + srow) * (DIM * 2) + scol * 16;
                __builtin_amdgcn_global_load_lds((g_u32*)g,
                    (lds_u32*)(mytile + issue * 1024 + lane * 0), 16, 0, 0);
            }
            __syncthreads();

            half8 af0[4], af1[4];
            #pragma unroll
            for (int ni = 0; ni < 4; ni++) {
                const char* base = af + (arow + ni * 16) * 128;
                af0[ni] = *reinterpret_cast<const half8*>(base + sw0);
                af1[ni] = *reinterpret_cast<const half8*>(base + sw1);
            }
            #pragma unroll
            for (int mi = 0; mi < 4; mi++) {
                const char* base = hf + (hrow + mi * 16) * 128;
                half8 hf0 = *reinterpret_cast<const half8*>(base + sw0);
                half8 hf1 = *reinterpret_cast<const half8*>(base + sw1);
                #pragma unroll
                for (int ni = 0; ni < 4; ni++) {
                    acc[mi][ni] = __builtin_amdgcn_mfma_f32_16x16x32_f16(hf0, af0[ni], acc[mi][ni], 0, 0, 0);
                    acc[mi][ni] = __builtin_amdgcn_mfma_f32_16x16x32_f16(hf1, af1[ni], acc[mi][ni], 0, 0, 0);
                }
            }
        }

        // fused top-2 update: 8 VALU per score
        const uint32_t metabase = (uint32_t)(it << 2);
        #pragma unroll
        for (int mi = 0; mi < 4; mi++)
            #pragma unroll
            for (int ni = 0; ni < 4; ni++) {
                const uint32_t meta = metabase | (uint32_t)ni;
                #pragma unroll
                for (int r = 0; r < 4; r++) {
                    uint32_t pk = (ford(acc[mi][ni][r]) & 0xFFFFFFC0u) | meta;
                    int s = mi * 4 + r;
                    uint32_t lo = umin32(v1[s], pk);
                    v1[s] = umax32(v1[s], pk);
                    v2[s] = umax32(v2[s], lo);
                }
            }
    }

    // block top-2 per row: two passes through LDS (stride 33 breaks conflicts)
    u64* cl = (u64*)smem;
    u64 g1 = 0, g2 = 0;
    for (int pass = 0; pass < 2; pass++) {
        __syncthreads();
        #pragma unroll
        for (int s = 0; s < 16; s++) {
            int mi = s >> 2, r = s & 3;
            int row_local = wm * 64 + mi * 16 + q * 4 + r;
            uint32_t pv = pass ? v2[s] : v1[s];
            uint32_t meta = pv & 63u;
            int k = (kslot + (int)(meta >> 2) * KSLOTS) * KT + wn * 64 + (int)(meta & 3u) * 16 + lr;
            u64 e = ((u64)(pv & 0xFFFFFFC0u) << 32) | (u64)(~(uint32_t)k);
            cl[row_local * 33 + wn * 16 + lr] = e;
        }
        __syncthreads();
        if (t < BT) {
            #pragma unroll 4
            for (int j = 0; j < 32; j++) {
                u64 e = cl[t * 33 + j];
                u64 lo = umin64(g1, e);
                g1 = umax64(g1, e);
                g2 = umax64(g2, lo);
            }
        }
    }
    if (t < BT) {
        size_t base = ((size_t)(b0 + t) * KSLOTS + kslot) * 2;
        cand[base] = g1;
        cand[base + 1] = g2;
    }
}

// one wave per row: top-4 of 48 candidates, exact fp32 rescore, argmax.
__global__ __launch_bounds__(256) void refine_kernel(
    const float* __restrict__ h, const float* __restrict__ A,
    const float* __restrict__ rn, const u64* __restrict__ cand,
    int* __restrict__ out)
{
    const int t = threadIdx.x, lane = t & 63, wid = t >> 6;
    const int row = blockIdx.x * 4 + wid;
    const u64* cr = cand + (size_t)row * (KSLOTS * 2);
    u64 x = (lane < KSLOTS * 2) ? cr[lane] : 0ULL;

    u64 sel[4];
    #pragma unroll
    for (int j = 0; j < 4; j++) {
        u64 v = x;
        #pragma unroll
        for (int m = 32; m >= 1; m >>= 1) v = umax64(v, __shfl_xor(v, m, 64));
        sel[j] = v;
        if (x == v) x = 0;
    }

    const fx4* hp = reinterpret_cast<const fx4*>(h + (size_t)row * DIM);
    fx4 h0 = hp[lane * 2], h1 = hp[lane * 2 + 1];

    u64 best = 0;
    #pragma unroll
    for (int j = 0; j < 4; j++) {
        uint32_t kg = ~(uint32_t)sel[j];
        const fx4* ap = reinterpret_cast<const fx4*>(A + (size_t)kg * DIM);
        fx4 a0 = ap[lane * 2], a1 = ap[lane * 2 + 1];
        float s = h0[0]*a0[0] + h0[1]*a0[1] + h0[2]*a0[2] + h0[3]*a0[3]
                + h1[0]*a1[0] + h1[1]*a1[1] + h1[2]*a1[2] + h1[3]*a1[3];
        #pragma unroll
        for (int m = 32; m >= 1; m >>= 1) s += __shfl_xor(s, m, 64);
        s *= rn[kg];
        u64 pk = ((u64)ford(s) << 32) | (u64)(~kg);
        best = umax64(best, pk);
    }
    if (lane == 0) out[row] = (int)(~(uint32_t)best);
}

extern "C" void kernel_launch(void* const* d_in, const int* in_sizes, int n_in,
                              void* d_out, int out_size, void* d_ws, size_t ws_size,
                              hipStream_t stream) {
    const float* h = (const float*)d_in[0];   // [4096, 512]
    const float* A = (const float*)d_in[1];   // [32768, 512]
    int* out = (int*)d_out;                   // [4096] int32

    // ws: a16 (32MB) | h16 (4MB) | rn (128KB) | cand (1.5MB)  ~= 37.7MB
    char* w = (char*)d_ws;
    f16* a16 = (f16*)w;
    f16* h16 = (f16*)(w + (size_t)K_ROWS * DIM * sizeof(f16));
    float* rn = (float*)(w + (size_t)(K_ROWS + B_ROWS) * DIM * sizeof(f16));
    u64* cand = (u64*)(w + (size_t)(K_ROWS + B_ROWS) * DIM * sizeof(f16)
                         + (size_t)K_ROWS * sizeof(float));

    prepA_kernel<<<K_ROWS / 4, 256, 0, stream>>>(A, a16, rn);
    preph_kernel<<<(B_ROWS * DIM / 8) / 256, 256, 0, stream>>>(h, h16);
    score_kernel<<<32 * KSLOTS, 256, 0, stream>>>(h16, a16, cand);
    refine_kernel<<<B_ROWS / 4, 256, 0, stream>>>(h, A, rn, cand, out);
}